// Round 2
// baseline (395.729 us; speedup 1.0000x reference)
//
#include <hip/hip_runtime.h>
#include <stdint.h>

typedef __attribute__((ext_vector_type(4))) float f32x4;
typedef __attribute__((ext_vector_type(8))) __bf16 bf16x8;

// ---------- helpers ----------
__device__ __forceinline__ unsigned short f2bf(float f) {
  union { float f; uint32_t u; } v; v.f = f;
  uint32_t u = v.u;
  return (unsigned short)((u + 0x7FFFu + ((u >> 16) & 1u)) >> 16);
}
__device__ __forceinline__ float bflo(uint32_t u) {
  union { uint32_t u; float f; } v; v.u = u << 16; return v.f;
}
__device__ __forceinline__ float bfhi(uint32_t u) {
  union { uint32_t u; float f; } v; v.u = u & 0xffff0000u; return v.f;
}

// proper addrspace casts: let the compiler emit addrspacecast (no integer
// round-trip -- truncating a flat LDS pointer to 32 bits is NOT the LDS offset)
__device__ __forceinline__ void async_copy16(void* lds, const void* g) {
  __builtin_amdgcn_global_load_lds(
      (const __attribute__((address_space(1))) void*)g,
      (__attribute__((address_space(3))) void*)lds,
      16, 0, 0);
}

// ---------- f32 -> bf16 convert (flat) ----------
__global__ void cvt_f32_bf16(const float* __restrict__ in,
                             uint32_t* __restrict__ out, int n) {
  int i = blockIdx.x * blockDim.x + threadIdx.x;
  int idx = i * 8;
  if (idx >= n) return;
  float4 a = *(const float4*)(in + idx);
  float4 b = *(const float4*)(in + idx + 4);
  uint4 o;
  o.x = f2bf(a.x) | ((uint32_t)f2bf(a.y) << 16);
  o.y = f2bf(a.z) | ((uint32_t)f2bf(a.w) << 16);
  o.z = f2bf(b.x) | ((uint32_t)f2bf(b.y) << 16);
  o.w = f2bf(b.z) | ((uint32_t)f2bf(b.w) << 16);
  *(uint4*)(out + i * 4) = o;
}

// ---------- f32 (R x C) -> bf16 transposed (C x R) ----------
__global__ void transpose_to_bf16(const float* __restrict__ in,
                                  unsigned short* __restrict__ out,
                                  int R, int C) {
  __shared__ float tile[32][33];
  int c0 = blockIdx.x * 32, r0 = blockIdx.y * 32;
  int tx = threadIdx.x, ty = threadIdx.y;   // 32 x 8
  #pragma unroll
  for (int rr = 0; rr < 32; rr += 8)
    tile[ty + rr][tx] = in[(size_t)(r0 + ty + rr) * C + c0 + tx];
  __syncthreads();
  #pragma unroll
  for (int rr = 0; rr < 32; rr += 8)
    out[(size_t)(c0 + ty + rr) * R + r0 + tx] = f2bf(tile[tx][ty + rr]);
}

// ---------- GEMM: C(MxN) = A(MxK) @ Bt(NxK)^T + bias ----------
// A, Bt bf16 row-major. 128x128 tile, BK=64, 4 waves (2x2), m97 structure.
template <bool OUT_BF16>
__global__ __launch_bounds__(256) void gemm_tn(
    const unsigned short* __restrict__ A,
    const unsigned short* __restrict__ Bt,
    const float* __restrict__ bias,
    void* __restrict__ Cout, int M, int N, int K) {
  constexpr int BK = 64;
  __shared__ unsigned short As[128 * BK];
  __shared__ unsigned short Bs[128 * BK];
  const int bm0 = blockIdx.x * 128;
  const int bn0 = blockIdx.y * 128;
  const int tid = threadIdx.x;
  const int wave = tid >> 6, lane = tid & 63;
  const int wm = wave >> 1, wn = wave & 1;

  f32x4 acc[4][4] = {};
  const int nk = K / BK;

  for (int kt = 0; kt < nk; ++kt) {
    const unsigned short* Ak = A + (size_t)bm0 * K + kt * BK;
    const unsigned short* Bk = Bt + (size_t)bn0 * K + kt * BK;
    #pragma unroll
    for (int i = 0; i < 4; ++i) {
      int chunk = wave * 4 + i;              // 16 chunks of 1KB each
      int row = chunk * 8 + (lane >> 3);     // 8 rows (128B) per chunk
      int cole = (lane & 7) * 8;             // element col within BK
      async_copy16((char*)As + chunk * 1024, Ak + (size_t)row * K + cole);
      async_copy16((char*)Bs + chunk * 1024, Bk + (size_t)row * K + cole);
    }
    __syncthreads();
    #pragma unroll
    for (int kk = 0; kk < 2; ++kk) {
      const int khi = kk * 32 + ((lane >> 4) & 3) * 8;
      bf16x8 af[4], bfr[4];
      #pragma unroll
      for (int a = 0; a < 4; ++a) {
        int row = wm * 64 + a * 16 + (lane & 15);
        af[a] = *(const bf16x8*)(As + row * BK + khi);
      }
      #pragma unroll
      for (int b = 0; b < 4; ++b) {
        int col = wn * 64 + b * 16 + (lane & 15);
        bfr[b] = *(const bf16x8*)(Bs + col * BK + khi);
      }
      #pragma unroll
      for (int a = 0; a < 4; ++a)
        #pragma unroll
        for (int b = 0; b < 4; ++b)
          acc[a][b] = __builtin_amdgcn_mfma_f32_16x16x32_bf16(
              af[a], bfr[b], acc[a][b], 0, 0, 0);
    }
    __syncthreads();
  }

  // epilogue: C/D layout col = lane&15, row = (lane>>4)*4 + reg
  #pragma unroll
  for (int a = 0; a < 4; ++a) {
    int mrow = bm0 + wm * 64 + a * 16 + ((lane >> 4) & 3) * 4;
    #pragma unroll
    for (int b = 0; b < 4; ++b) {
      int ncol = bn0 + wn * 64 + b * 16 + (lane & 15);
      float bias_v = bias[ncol];
      #pragma unroll
      for (int r = 0; r < 4; ++r) {
        float v = acc[a][b][r] + bias_v;
        size_t off = (size_t)(mrow + r) * N + ncol;
        if (OUT_BF16) ((unsigned short*)Cout)[off] = f2bf(v);
        else          ((float*)Cout)[off] = v;
      }
    }
  }
}

// ---------- energy + mask + softmax -> P (f32, 8192 x 64) ----------
// One wave per token. lane = i*8 + j. energy[i][j] = dot512(Q[i], K[j])/sqrt(512)
__global__ __launch_bounds__(256) void energy_kernel(
    const unsigned short* __restrict__ Q,
    const unsigned short* __restrict__ Kb,
    const int* __restrict__ mask,
    float* __restrict__ P) {
  const int wave = threadIdx.x >> 6, lane = threadIdx.x & 63;
  const int t = blockIdx.x * 4 + wave;       // token id, 0..8191
  const unsigned short* Qr = Q + (size_t)t * 4096;
  const unsigned short* Kr = Kb + (size_t)t * 4096;
  const int i = lane >> 3, j = lane & 7;

  float e = 0.f;
  #pragma unroll 4
  for (int d = 0; d < 512; d += 8) {
    uint4 q4 = *(const uint4*)(Qr + i * 512 + d);
    uint4 k4 = *(const uint4*)(Kr + j * 512 + d);
    e += bflo(q4.x) * bflo(k4.x) + bfhi(q4.x) * bfhi(k4.x);
    e += bflo(q4.y) * bflo(k4.y) + bfhi(q4.y) * bfhi(k4.y);
    e += bflo(q4.z) * bflo(k4.z) + bfhi(q4.z) * bfhi(k4.z);
    e += bflo(q4.w) * bflo(k4.w) + bfhi(q4.w) * bfhi(k4.w);
  }
  e *= 0.044194173824159216f;                 // 1/sqrt(512)
  if (mask[(size_t)t * 64 + lane] == 0) e = -1e30f;

  float m = e;
  #pragma unroll
  for (int s = 1; s < 8; s <<= 1) m = fmaxf(m, __shfl_xor(m, s, 64));
  float p = __expf(e - m);
  float sum = p;
  #pragma unroll
  for (int s = 1; s < 8; s <<= 1) sum += __shfl_xor(sum, s, 64);
  P[(size_t)t * 64 + lane] = p / sum;
}

// ---------- PV: out2 rows in the (B,H,L,E)->(B,L,H*E) reshaped layout ----------
__global__ __launch_bounds__(256) void pv_kernel(
    const float* __restrict__ P,
    const unsigned short* __restrict__ Vb,
    unsigned short* __restrict__ out2) {
  const int wave = threadIdx.x >> 6, lane = threadIdx.x & 63;
  const int t = blockIdx.x * 4 + wave;       // token id, 0..8191
  const unsigned short* Vr = Vb + (size_t)t * 4096;
  float att = P[(size_t)t * 64 + lane];

  const int nb = t >> 11, l = t & 2047;
  const size_t tok_base = (size_t)nb * 8388608 + (size_t)(l >> 3) * 4096 +
                          (size_t)(l & 7) * 512 + lane * 8;
  #pragma unroll
  for (int hh = 0; hh < 8; ++hh) {
    float accv[8] = {0.f, 0.f, 0.f, 0.f, 0.f, 0.f, 0.f, 0.f};
    #pragma unroll
    for (int jj = 0; jj < 8; ++jj) {
      float a = __shfl(att, hh * 8 + jj, 64);
      uint4 v4 = *(const uint4*)(Vr + jj * 512 + lane * 8);
      accv[0] += a * bflo(v4.x); accv[1] += a * bfhi(v4.x);
      accv[2] += a * bflo(v4.y); accv[3] += a * bfhi(v4.y);
      accv[4] += a * bflo(v4.z); accv[5] += a * bfhi(v4.z);
      accv[6] += a * bflo(v4.w); accv[7] += a * bfhi(v4.w);
    }
    uint4 o;
    o.x = f2bf(accv[0]) | ((uint32_t)f2bf(accv[1]) << 16);
    o.y = f2bf(accv[2]) | ((uint32_t)f2bf(accv[3]) << 16);
    o.z = f2bf(accv[4]) | ((uint32_t)f2bf(accv[5]) << 16);
    o.w = f2bf(accv[6]) | ((uint32_t)f2bf(accv[7]) << 16);
    *(uint4*)(out2 + tok_base + (size_t)hh * 1048576) = o;   // hh*256*4096
  }
}

// ---------- launch ----------
extern "C" void kernel_launch(void* const* d_in, const int* in_sizes, int n_in,
                              void* d_out, int out_size, void* d_ws, size_t ws_size,
                              hipStream_t stream) {
  const float* values  = (const float*)d_in[0];
  const float* keys    = (const float*)d_in[1];
  const float* queries = (const float*)d_in[2];
  const int*   mask    = (const int*)d_in[3];
  const float* Wv = (const float*)d_in[4];
  const float* bv = (const float*)d_in[5];
  const float* Wk = (const float*)d_in[6];
  const float* bk = (const float*)d_in[7];
  const float* Wq = (const float*)d_in[8];
  const float* bq = (const float*)d_in[9];
  const float* Wo = (const float*)d_in[10];
  const float* bo = (const float*)d_in[11];

  // workspace layout -- peak 178 MB (two 67MB buffers, reused):
  unsigned short* xv  = (unsigned short*)d_ws;            // 8192*512
  unsigned short* xk  = xv + 8192 * 512;
  unsigned short* xq  = xk + 8192 * 512;
  unsigned short* Wvt = xq + 8192 * 512;                  // 4096*512 (N x K)
  unsigned short* Wkt = Wvt + 4096 * 512;
  unsigned short* Wqt = Wkt + 4096 * 512;
  unsigned short* Wot = Wqt + 4096 * 512;                 // 512*4096 (N x K)
  float*          P   = (float*)(Wot + 4096 * 512);       // 8192*64 f32
  unsigned short* bufA = (unsigned short*)(P + 8192 * 64); // 8192*4096 bf16
  unsigned short* bufB = bufA + (size_t)8192 * 4096;       // 8192*4096 bf16

  const int nx = 8192 * 512;
  cvt_f32_bf16<<<nx / 8 / 256, 256, 0, stream>>>(values, (uint32_t*)xv, nx);
  cvt_f32_bf16<<<nx / 8 / 256, 256, 0, stream>>>(keys, (uint32_t*)xk, nx);
  cvt_f32_bf16<<<nx / 8 / 256, 256, 0, stream>>>(queries, (uint32_t*)xq, nx);

  transpose_to_bf16<<<dim3(4096 / 32, 512 / 32), dim3(32, 8), 0, stream>>>(Wv, Wvt, 512, 4096);
  transpose_to_bf16<<<dim3(4096 / 32, 512 / 32), dim3(32, 8), 0, stream>>>(Wk, Wkt, 512, 4096);
  transpose_to_bf16<<<dim3(4096 / 32, 512 / 32), dim3(32, 8), 0, stream>>>(Wq, Wqt, 512, 4096);
  transpose_to_bf16<<<dim3(512 / 32, 4096 / 32), dim3(32, 8), 0, stream>>>(Wo, Wot, 4096, 512);

  dim3 g1(8192 / 128, 4096 / 128);
  // Q -> bufA, K -> bufB
  gemm_tn<true><<<g1, 256, 0, stream>>>(xq, Wqt, bq, bufA, 8192, 4096, 512);
  gemm_tn<true><<<g1, 256, 0, stream>>>(xk, Wkt, bk, bufB, 8192, 4096, 512);

  // energy + softmax -> P  (Q, K dead afterwards)
  energy_kernel<<<8192 / 4, 256, 0, stream>>>(bufA, bufB, mask, P);

  // V -> bufA (overwrites Q)
  gemm_tn<true><<<g1, 256, 0, stream>>>(xv, Wvt, bv, bufA, 8192, 4096, 512);

  // PV -> bufB (overwrites K)
  pv_kernel<<<8192 / 4, 256, 0, stream>>>(P, bufA, bufB);

  // final: out = bufB @ Wo^T + bo  (f32 out)
  gemm_tn<false><<<dim3(8192 / 128, 512 / 128), 256, 0, stream>>>(
      bufB, Wot, bo, d_out, 8192, 512, 4096);
}